// Round 4
// baseline (8988.360 us; speedup 1.0000x reference)
//
#include <hip/hip_runtime.h>
#include <math.h>
#include <stdint.h>

#define BATCH  8192
#define HIDDEN 512
#define VOCAB  128
#define NSTEP  127   // SEQ_LEN - 1
#define OUTROW (NSTEP * VOCAB)
#define NG     2048  // 4*HIDDEN gate columns

using half8   = __attribute__((ext_vector_type(8))) _Float16;
using half4   = __attribute__((ext_vector_type(4))) _Float16;
using float4v = __attribute__((ext_vector_type(4))) float;

#define GLD16(g, l) __builtin_amdgcn_global_load_lds( \
    (const __attribute__((address_space(1))) void*)(g), \
    (__attribute__((address_space(3))) void*)(l), 16, 0, 0)

__device__ __forceinline__ float fast_rcp(float x) { return __builtin_amdgcn_rcpf(x); }
__device__ __forceinline__ float fast_sig(float x) { return fast_rcp(1.0f + __expf(-x)); }
__device__ __forceinline__ float fast_tanh(float x) { return 1.0f - 2.0f * fast_rcp(1.0f + __expf(2.0f * x)); }

// permuted gate-column index -> original W row (gate*512 + jj)
__device__ __forceinline__ int orig_row_of(int np) {
    int bn = np >> 7, cc = np & 127;
    int wv = cc >> 6, cw = cc & 63;
    int gate = cw >> 4, jjl = cw & 15;
    int jj = bn * 32 + wv * 16 + jjl;
    return gate * HIDDEN + jj;
}

__global__ __launch_bounds__(256) void init_tok_kernel(int* __restrict__ tok) {
    int i = blockIdx.x * 256 + threadIdx.x;
    if (i < BATCH) tok[i] = 0;
}

__global__ __launch_bounds__(256) void prep_whh_kernel(
    const float* __restrict__ Whh, _Float16* __restrict__ wh, _Float16* __restrict__ wl)
{
    int np = blockIdx.x;
    int orig = orig_row_of(np);
    for (int k = threadIdx.x; k < HIDDEN; k += 256) {
        float w = Whh[(size_t)orig * HIDDEN + k] * 2048.0f;
        _Float16 h = (_Float16)w;
        wh[(size_t)np * HIDDEN + k] = h;
        wl[(size_t)np * HIDDEN + k] = (_Float16)(w - (float)h);
    }
}

// wih4[v][jj] = float4 of the 4 gate W_ih entries for col v; bcomb4[jj] likewise
__global__ __launch_bounds__(128) void prep_wih4_kernel(
    const float* __restrict__ Wih, const float* __restrict__ bih,
    const float* __restrict__ bhh, float4* __restrict__ wih4, float4* __restrict__ bcomb4)
{
    int jj = blockIdx.x;               // 0..511
    int v  = threadIdx.x;              // 0..127
    float4 w;
    w.x = Wih[(size_t)(0 * HIDDEN + jj) * VOCAB + v];
    w.y = Wih[(size_t)(1 * HIDDEN + jj) * VOCAB + v];
    w.z = Wih[(size_t)(2 * HIDDEN + jj) * VOCAB + v];
    w.w = Wih[(size_t)(3 * HIDDEN + jj) * VOCAB + v];
    wih4[(size_t)v * HIDDEN + jj] = w;
    if (v == 0) {
        float4 b;
        b.x = bih[0 * HIDDEN + jj] + bhh[0 * HIDDEN + jj];
        b.y = bih[1 * HIDDEN + jj] + bhh[1 * HIDDEN + jj];
        b.z = bih[2 * HIDDEN + jj] + bhh[2 * HIDDEN + jj];
        b.w = bih[3 * HIDDEN + jj] + bhh[3 * HIDDEN + jj];
        bcomb4[jj] = b;
    }
}

__global__ __launch_bounds__(256) void prep_wfc_kernel(
    const float* __restrict__ Wfc, _Float16* __restrict__ wh, _Float16* __restrict__ wl)
{
    int i = blockIdx.x * 256 + threadIdx.x;
    float w = Wfc[i] * 2048.0f;
    _Float16 h = (_Float16)w;
    wh[i] = h;
    wl[i] = (_Float16)(w - (float)h);
}

__global__ __launch_bounds__(256) void prep_z_kernel(
    const float* __restrict__ z, _Float16* __restrict__ zh, _Float16* __restrict__ zl)
{
    int i = blockIdx.x * 256 + threadIdx.x;
    float4 v = ((const float4*)z)[i];
    float s0 = v.x * 2048.f, s1 = v.y * 2048.f, s2 = v.z * 2048.f, s3 = v.w * 2048.f;
    _Float16 h0 = (_Float16)s0, h1 = (_Float16)s1, h2 = (_Float16)s2, h3 = (_Float16)s3;
    half4 H = {h0, h1, h2, h3};
    half4 L = {(_Float16)(s0 - (float)h0), (_Float16)(s1 - (float)h1),
               (_Float16)(s2 - (float)h2), (_Float16)(s3 - (float)h3)};
    ((half4*)zh)[i] = H;
    ((half4*)zl)[i] = L;
}

// c0 = relu(z @ W_cz^T + b_cz), fp32 (runs once)
__global__ __launch_bounds__(256) void c0_kernel(
    const float* __restrict__ z, const float* __restrict__ Wcz,
    const float* __restrict__ bcz, float* __restrict__ c)
{
    __shared__ float As[16][128];
    __shared__ float Bs[16][128];
    const int m0 = blockIdx.x * 128;
    const int n0 = blockIdx.y * 128;
    const int tid = threadIdx.x;
    const int ty = tid >> 4, tx = tid & 15;

    float acc[8][8];
#pragma unroll
    for (int i = 0; i < 8; ++i)
#pragma unroll
        for (int j = 0; j < 8; ++j) acc[i][j] = 0.f;

    for (int kc = 0; kc < HIDDEN; kc += 16) {
#pragma unroll
        for (int i = 0; i < 2; ++i) {
            int id = tid * 2 + i;
            int row = id >> 2;
            int kq = (id & 3) * 4;
            float4 av = *(const float4*)(z + (size_t)(m0 + row) * HIDDEN + kc + kq);
            As[kq + 0][row] = av.x; As[kq + 1][row] = av.y;
            As[kq + 2][row] = av.z; As[kq + 3][row] = av.w;
            float4 bv = *(const float4*)(Wcz + (size_t)(n0 + row) * HIDDEN + kc + kq);
            Bs[kq + 0][row] = bv.x; Bs[kq + 1][row] = bv.y;
            Bs[kq + 2][row] = bv.z; Bs[kq + 3][row] = bv.w;
        }
        __syncthreads();
#pragma unroll 4
        for (int k = 0; k < 16; ++k) {
            float a[8], b[8];
            *(float4*)&a[0] = *(const float4*)&As[k][ty * 8];
            *(float4*)&a[4] = *(const float4*)&As[k][ty * 8 + 4];
            *(float4*)&b[0] = *(const float4*)&Bs[k][tx * 8];
            *(float4*)&b[4] = *(const float4*)&Bs[k][tx * 8 + 4];
#pragma unroll
            for (int i = 0; i < 8; ++i)
#pragma unroll
                for (int j = 0; j < 8; ++j)
                    acc[i][j] = fmaf(a[i], b[j], acc[i][j]);
        }
        __syncthreads();
    }
#pragma unroll
    for (int i = 0; i < 8; ++i) {
        int m = m0 + ty * 8 + i;
#pragma unroll
        for (int j = 0; j < 8; ++j) {
            int n = n0 + tx * 8 + j;
            c[(size_t)m * HIDDEN + n] = fmaxf(acc[i][j] + bcz[n], 0.f);
        }
    }
}

// Fused LSTM step. Block 128(M) x 256(N'), 4 waves 1x4, wave tile 128x64.
// fp16x3 split MFMA. A staged via global_load_lds (shared x4 waves, XOR swizzle);
// B (wave-private whh rows) loaded DIRECTLY global->VGPR (no LDS round-trip).
__global__ __launch_bounds__(256, 2) void lstm_mfma_kernel(
    const _Float16* __restrict__ hin_h, const _Float16* __restrict__ hin_l,
    const _Float16* __restrict__ whh_h, const _Float16* __restrict__ whh_l,
    const float4* __restrict__ wih4, const float4* __restrict__ bcomb4,
    const int* __restrict__ tok, float* __restrict__ c,
    _Float16* __restrict__ hout_h, _Float16* __restrict__ hout_l)
{
    __shared__ _Float16 As_h[128][32];
    __shared__ _Float16 As_l[128][32];
    __shared__ int tok_s[128];

    const int tid  = threadIdx.x;
    const int wid  = tid >> 6, lane = tid & 63;
    const int m0   = blockIdx.x * 128;
    const int n0   = blockIdx.y * 256;

    float4v acc[8][4];
#pragma unroll
    for (int i = 0; i < 8; ++i)
#pragma unroll
        for (int j = 0; j < 4; ++j) acc[i][j] = (float4v){0.f, 0.f, 0.f, 0.f};

    if (tid < 128) tok_s[tid] = tok[m0 + tid];

    // A staging: wave wid stages rows [wid*32, wid*32+32); XOR chunk swizzle
    const int lrow = lane >> 2;
    const int lchk = (lane & 3) ^ ((lane >> 3) & 3);
    const int loff = lrow * HIDDEN + lchk * 8;
    const _Float16* agh = hin_h + (size_t)(m0 + wid * 32) * HIDDEN + loff;
    const _Float16* agl = hin_l + (size_t)(m0 + wid * 32) * HIDDEN + loff;

    // fragment indices
    const int t = lane & 15, qr = lane >> 4;
    const int qa = (qr ^ ((t >> 1) & 3)) * 8;

    // B direct-load base: row n0 + wid*64 + t, k-offset qr*8
    const _Float16* bgh = whh_h + (size_t)(n0 + wid * 64 + t) * HIDDEN + qr * 8;
    const _Float16* bgl = whh_l + (size_t)(n0 + wid * 64 + t) * HIDDEN + qr * 8;

    for (int kc = 0; kc < HIDDEN; kc += 32) {
        GLD16(agh + kc,               &As_h[wid * 32][0]);
        GLD16(agh + kc + 16 * HIDDEN, &As_h[wid * 32 + 16][0]);
        GLD16(agl + kc,               &As_l[wid * 32][0]);
        GLD16(agl + kc + 16 * HIDDEN, &As_l[wid * 32 + 16][0]);

        half8 bh[4], bl[4];
#pragma unroll
        for (int j = 0; j < 4; ++j) {
            bh[j] = *(const half8*)(bgh + (size_t)j * 16 * HIDDEN + kc);
            bl[j] = *(const half8*)(bgl + (size_t)j * 16 * HIDDEN + kc);
        }
        __syncthreads();

#pragma unroll
        for (int i = 0; i < 8; ++i) {
            half8 ah = *(const half8*)&As_h[i * 16 + t][qa];
            half8 al = *(const half8*)&As_l[i * 16 + t][qa];
#pragma unroll
            for (int j = 0; j < 4; ++j) {
                acc[i][j] = __builtin_amdgcn_mfma_f32_16x16x32_f16(ah, bh[j], acc[i][j], 0, 0, 0);
                acc[i][j] = __builtin_amdgcn_mfma_f32_16x16x32_f16(ah, bl[j], acc[i][j], 0, 0, 0);
                acc[i][j] = __builtin_amdgcn_mfma_f32_16x16x32_f16(al, bh[j], acc[i][j], 0, 0, 0);
            }
        }
        __syncthreads();
    }

    // epilogue: lane t owns jj; gates i/f/g/o in acc[.][0..3]
    const float INV22 = 1.0f / 4194304.0f;   // 2^-22
    const int g  = blockIdx.y * 4 + wid;
    const int jj = (g >> 1) * 32 + (g & 1) * 16 + t;
    const float4 b4 = bcomb4[jj];
    const float4* wjj = wih4 + jj;

#pragma unroll
    for (int i = 0; i < 8; ++i) {
        int mb = i * 16 + qr * 4;
#pragma unroll
        for (int r = 0; r < 4; ++r) {
            int ml = mb + r;
            int m  = m0 + ml;
            int tk = tok_s[ml];
            float4 w4 = wjj[(size_t)tk * HIDDEN];
            float iv = acc[i][0][r] * INV22 + b4.x + w4.x;
            float fv = acc[i][1][r] * INV22 + b4.y + w4.y;
            float gv = acc[i][2][r] * INV22 + b4.z + w4.z;
            float ov = acc[i][3][r] * INV22 + b4.w + w4.w;
            float ig = fast_sig(iv);
            float fg = fast_sig(fv);
            float gg = fast_tanh(gv);
            float og = fast_sig(ov);
            size_t ci = (size_t)m * HIDDEN + jj;
            float cn = fg * c[ci] + ig * gg;
            c[ci] = cn;
            float hn = og * fast_tanh(cn);
            float hs = hn * 2048.f;
            _Float16 hh = (_Float16)hs;
            hout_h[ci] = hh;
            hout_l[ci] = (_Float16)(hs - (float)hh);
        }
    }
}

// logits = relu(h @ W_fc^T + b_fc) via fp16x3 MFMA; out[:,t,:]; tok = argmax.
// Block 32(M) x 128(N), 128 threads = 2 waves; wave w covers cols [w*64, w*64+64).
// A staged via GLD16 (shared), B (wfc, wave-private) loaded direct global->VGPR.
__global__ __launch_bounds__(128) void logits_mfma_kernel(
    const _Float16* __restrict__ hh_, const _Float16* __restrict__ hl_,
    const _Float16* __restrict__ wfc_h, const _Float16* __restrict__ wfc_l,
    const float* __restrict__ b_fc, float* __restrict__ out_t, int* __restrict__ tok)
{
    __shared__ _Float16 Ah[32][64];
    __shared__ _Float16 Al[32][64];
    __shared__ float redv[32][2];
    __shared__ int   redi[32][2];

    const int tid = threadIdx.x;
    const int wid = tid >> 6, lane = tid & 63;
    const int m0  = blockIdx.x * 32;
    const int t   = lane & 15, qr = lane >> 4;

    float4v acc[2][4];
#pragma unroll
    for (int im = 0; im < 2; ++im)
#pragma unroll
        for (int j = 0; j < 4; ++j) acc[im][j] = (float4v){0.f, 0.f, 0.f, 0.f};

    // A staging: wave0 -> Ah plane, wave1 -> Al plane; 8 rows per GLD16, swizzled
    const int lrow = lane >> 3;
    const int lchk = (lane & 7) ^ lrow;
    const int loff = lrow * HIDDEN + lchk * 8;
    const _Float16* Ag = (wid == 0 ? hh_ : hl_) + (size_t)m0 * HIDDEN + loff;
    _Float16* Adst = (wid == 0) ? &Ah[0][0] : &Al[0][0];

    const int sa = t & 7;   // fragment swizzle key

    // B direct base: row (vocab col) = wid*64 + j*16 + t
    const _Float16* bgh = wfc_h + (size_t)(wid * 64 + t) * HIDDEN + qr * 8;
    const _Float16* bgl = wfc_l + (size_t)(wid * 64 + t) * HIDDEN + qr * 8;

    for (int kc = 0; kc < HIDDEN; kc += 64) {
#pragma unroll
        for (int s = 0; s < 4; ++s)
            GLD16(Ag + kc + s * 8 * HIDDEN, Adst + (s * 8) * 64);

        half8 bh[4][2], bl[4][2];
#pragma unroll
        for (int j = 0; j < 4; ++j)
#pragma unroll
            for (int kh = 0; kh < 2; ++kh) {
                bh[j][kh] = *(const half8*)(bgh + (size_t)j * 16 * HIDDEN + kc + kh * 32);
                bl[j][kh] = *(const half8*)(bgl + (size_t)j * 16 * HIDDEN + kc + kh * 32);
            }
        __syncthreads();

#pragma unroll
        for (int kh = 0; kh < 2; ++kh) {
            int q = kh * 4 + qr;
#pragma unroll
            for (int im = 0; im < 2; ++im) {
                half8 a_h = *(const half8*)&Ah[im * 16 + t][(q ^ sa) * 8];
                half8 a_l = *(const half8*)&Al[im * 16 + t][(q ^ sa) * 8];
#pragma unroll
                for (int j = 0; j < 4; ++j) {
                    acc[im][j] = __builtin_amdgcn_mfma_f32_16x16x32_f16(a_h, bh[j][kh], acc[im][j], 0, 0, 0);
                    acc[im][j] = __builtin_amdgcn_mfma_f32_16x16x32_f16(a_h, bl[j][kh], acc[im][j], 0, 0, 0);
                    acc[im][j] = __builtin_amdgcn_mfma_f32_16x16x32_f16(a_l, bh[j][kh], acc[im][j], 0, 0, 0);
                }
            }
        }
        __syncthreads();
    }

    const float INV22 = 1.0f / 4194304.0f;
    float bv[4];
#pragma unroll
    for (int j = 0; j < 4; ++j) bv[j] = b_fc[wid * 64 + j * 16 + t];

#pragma unroll
    for (int im = 0; im < 2; ++im) {
#pragma unroll
        for (int r = 0; r < 4; ++r) {
            int row = im * 16 + qr * 4 + r;
            int m   = m0 + row;
            float vbest = -1.0f; int ibest = 0;
            float* op = out_t + (size_t)m * OUTROW + wid * 64 + t;
#pragma unroll
            for (int j = 0; j < 4; ++j) {
                float x = fmaxf(acc[im][j][r] * INV22 + bv[j], 0.f);
                op[j * 16] = x;
                int col = wid * 64 + j * 16 + t;
                if (x > vbest) { vbest = x; ibest = col; }
            }
            // reduce over the 16 lanes (t) of this quad-row
#pragma unroll
            for (int d = 1; d < 16; d <<= 1) {
                float vo = __shfl_xor(vbest, d, 64);
                int   io = __shfl_xor(ibest, d, 64);
                if (vo > vbest || (vo == vbest && io < ibest)) { vbest = vo; ibest = io; }
            }
            if (t == 0) { redv[row][wid] = vbest; redi[row][wid] = ibest; }
        }
    }
    __syncthreads();
    if (tid < 32) {
        float v0 = redv[tid][0], v1 = redv[tid][1];
        int   i0 = redi[tid][0], i1 = redi[tid][1];
        // wave0 cols are lower indices: strict > keeps lowest on ties
        tok[m0 + tid] = (v1 > v0) ? i1 : i0;
    }
}

extern "C" void kernel_launch(void* const* d_in, const int* in_sizes, int n_in,
                              void* d_out, int out_size, void* d_ws, size_t ws_size,
                              hipStream_t stream)
{
    const float* z    = (const float*)d_in[0];
    const float* W_ih = (const float*)d_in[1];
    const float* W_hh = (const float*)d_in[2];
    const float* b_ih = (const float*)d_in[3];
    const float* b_hh = (const float*)d_in[4];
    const float* W_cz = (const float*)d_in[5];
    const float* b_cz = (const float*)d_in[6];
    const float* W_fc = (const float*)d_in[7];
    const float* b_fc = (const float*)d_in[8];
    float* out = (float*)d_out;

    uint8_t* p = (uint8_t*)d_ws;
    float* c = (float*)p;            p += (size_t)BATCH * HIDDEN * 4;   // 16 MB
    _Float16* sA_h = (_Float16*)p;   p += (size_t)BATCH * HIDDEN * 2;   // 8 MB each
    _Float16* sA_l = (_Float16*)p;   p += (size_t)BATCH * HIDDEN * 2;
    _Float16* sB_h = (_Float16*)p;   p += (size_t)BATCH * HIDDEN * 2;
    _Float16* sB_l = (_Float16*)p;   p += (size_t)BATCH * HIDDEN * 2;
    _Float16* whhh = (_Float16*)p;   p += (size_t)NG * HIDDEN * 2;      // 2 MB each
    _Float16* whhl = (_Float16*)p;   p += (size_t)NG * HIDDEN * 2;
    _Float16* wfch = (_Float16*)p;   p += (size_t)VOCAB * HIDDEN * 2;   // 128 KB each
    _Float16* wfcl = (_Float16*)p;   p += (size_t)VOCAB * HIDDEN * 2;
    float4* wih4   = (float4*)p;     p += (size_t)VOCAB * HIDDEN * 16;  // 1 MB
    float4* bcomb4 = (float4*)p;     p += (size_t)HIDDEN * 16;          // 8 KB
    int* tokp      = (int*)p;        p += (size_t)BATCH * 4;

    init_tok_kernel<<<BATCH / 256, 256, 0, stream>>>(tokp);
    prep_whh_kernel<<<NG, 256, 0, stream>>>(W_hh, whhh, whhl);
    prep_wih4_kernel<<<HIDDEN, 128, 0, stream>>>(W_ih, b_ih, b_hh, wih4, bcomb4);
    prep_wfc_kernel<<<(VOCAB * HIDDEN) / 256, 256, 0, stream>>>(W_fc, wfch, wfcl);
    prep_z_kernel<<<(BATCH * HIDDEN / 4) / 256, 256, 0, stream>>>(z, sA_h, sA_l);
    c0_kernel<<<dim3(BATCH / 128, HIDDEN / 128), 256, 0, stream>>>(z, W_cz, b_cz, c);

    for (int t = 0; t < NSTEP; ++t) {
        const _Float16* inh = (t & 1) ? sB_h : sA_h;
        const _Float16* inl = (t & 1) ? sB_l : sA_l;
        _Float16* outh = (t & 1) ? sA_h : sB_h;
        _Float16* outl = (t & 1) ? sA_l : sB_l;
        lstm_mfma_kernel<<<dim3(BATCH / 128, NG / 256), 256, 0, stream>>>(
            inh, inl, whhh, whhl, wih4, bcomb4, tokp, c, outh, outl);
        logits_mfma_kernel<<<BATCH / 32, 128, 0, stream>>>(
            outh, outl, wfch, wfcl, b_fc, out + (size_t)t * VOCAB, tokp);
    }
}